// Round 4
// baseline (1152.408 us; speedup 1.0000x reference)
//
#include <hip/hip_runtime.h>
#include <stdint.h>

#define NB3 8112
#define NB4 2028
#define NB5 507
#define NTOT 10647           // 8112 + 2028 + 507
#define NBATCH 4
#define NCLS 20
#define NW32 333             // ceil(10647 / 32)
#define NW64 167             // ceil(10647 / 64)
#define NG 42                // ceil(NW64 / 4): groups of 256 boxes (4 u64 words)
#define LDS_CAP 9984         // boxes staged in LDS (fallback kernel)
#define CONF_THR_F 0.1f
#define IOU_THR_F 0.45f

typedef unsigned long long u64;

// ---------------------------------------------------------------------------
// Kernel A: per-box score / class argmax / sort key
// ---------------------------------------------------------------------------
__global__ void prep_kernel(const float* __restrict__ p3b, const float* __restrict__ p3c, const float* __restrict__ p3k,
                            const float* __restrict__ p4b, const float* __restrict__ p4c, const float* __restrict__ p4k,
                            const float* __restrict__ p5b, const float* __restrict__ p5c, const float* __restrict__ p5k,
                            uint64_t* __restrict__ keys, float4* __restrict__ boxes_cat,
                            float* __restrict__ score, int* __restrict__ clsidx, uint32_t* __restrict__ svout)
{
#pragma clang fp contract(off)
    int idx = blockIdx.x * 256 + threadIdx.x;
    if (idx >= NBATCH * NTOT) return;
    int b = idx / NTOT;
    int i = idx - b * NTOT;

    const float* bx; const float* cf; const float* cl; int n, off;
    if (i < NB3)            { bx = p3b; cf = p3c; cl = p3k; n = NB3; off = i; }
    else if (i < NB3 + NB4) { bx = p4b; cf = p4c; cl = p4k; n = NB4; off = i - NB3; }
    else                    { bx = p5b; cf = p5c; cl = p5k; n = NB5; off = i - NB3 - NB4; }

    size_t e = (size_t)b * n + off;
    float4 box = *(const float4*)(bx + e * 4);
    float conf = cf[e];
    const float* c = cl + e * NCLS;
    float m = c[0]; int mi = 0;
    #pragma unroll
    for (int k = 1; k < NCLS; ++k) { float v = c[k]; if (v > m) { m = v; mi = k; } }

    bool valid = conf > CONF_THR_F;
    float s = valid ? conf * m : 0.0f;           // exact: single f32 mul, no fma
    uint32_t sb = __float_as_uint(s);            // s >= 0 -> bits monotonic
    keys[idx]      = ((uint64_t)sb << 32) | (uint32_t)(0xFFFFFFFFu - (uint32_t)i);
    boxes_cat[idx] = box;
    score[idx]     = s;
    clsidx[idx]    = mi;
    svout[idx]     = valid ? 1u : 0u;
}

// ---------------------------------------------------------------------------
// Kernel B: stable descending rank sort (rank = #keys strictly greater),
// scatter sorted arrays, build valid bitmap (u64 words) per image
// ---------------------------------------------------------------------------
__global__ void rank_kernel(const uint64_t* __restrict__ keys,
                            const float4* __restrict__ boxes_cat,
                            const float* __restrict__ score,
                            const int* __restrict__ clsidx,
                            const uint32_t* __restrict__ sv,
                            float4* __restrict__ sboxes, float* __restrict__ sscore,
                            int* __restrict__ scls, uint32_t* __restrict__ ssv,
                            u64* __restrict__ validbits, int* __restrict__ nvalid)
{
    int b = blockIdx.y;
    int i = blockIdx.x * 256 + threadIdx.x;
    const uint64_t* kb = keys + (size_t)b * NTOT;
    uint64_t mykey = (i < NTOT) ? kb[i] : 0ull;

    __shared__ uint64_t tile[256];
    int rank = 0;
    for (int t0 = 0; t0 < NTOT; t0 += 256) {
        int j = t0 + threadIdx.x;
        tile[threadIdx.x] = (j < NTOT) ? kb[j] : 0ull;   // 0 never > any real key
        __syncthreads();
        #pragma unroll 8
        for (int t = 0; t < 256; ++t) rank += (tile[t] > mykey) ? 1 : 0;
        __syncthreads();
    }

    if (i < NTOT) {
        size_t src = (size_t)b * NTOT + i;
        size_t dst = (size_t)b * NTOT + rank;
        sboxes[dst] = boxes_cat[src];
        sscore[dst] = score[src];
        scls[dst]   = clsidx[src];
        uint32_t v  = sv[src];
        ssv[dst]    = v;
        if (v) {
            atomicOr(&validbits[(size_t)b * NW64 + (rank >> 6)], 1ull << (rank & 63));
            atomicMax(&nvalid[b], rank + 1);
        }
    }
}

// ---------------------------------------------------------------------------
// Kernel C1 (fast path): build suppression bit-matrix + band buffers.
// mask[(b*NTOT + i)*NW64 + c]: bit k set iff IoU(i, c*64+k)>thr and c*64+k > i.
// Only upper-triangle chunks (c >= r) are written.
// bdiag  (plane-major): bdiag[((b*NG+gi)*4 + (c&3))*256 + (i&255)] = m for
//   chunks in row i's own 256-group band (c>>2 == gi). Sub-diagonal chunks of
//   the band (c < i>>6) stay garbage -- provably dead (ffs-ascending greedy).
// nbdiag (row-major):  nbdiag[((b*NG+gi)*256 + (i&255))*4 + (c&3)] = m for
//   chunks in the NEXT group's band (c>>2 == gi+1); always above-diagonal.
// ---------------------------------------------------------------------------
__global__ void __launch_bounds__(256) mask_build(const float4* __restrict__ sboxes,
                                                  u64* __restrict__ mask,
                                                  u64* __restrict__ bdiag,
                                                  u64* __restrict__ nbdiag)
{
#pragma clang fp contract(off)
    int c = blockIdx.y;
    if (c < blockIdx.x * 4) return;              // whole block below diagonal
    int b = blockIdx.z;
    int sub = threadIdx.x >> 6;
    int lane = threadIdx.x & 63;
    int r = blockIdx.x * 4 + sub;

    __shared__ float4 cb[64];
    __shared__ float  ca[64];
    if (threadIdx.x < 64) {
        int j = c * 64 + threadIdx.x;
        float4 bj = sboxes[(size_t)b * NTOT + (j < NTOT ? j : NTOT - 1)];
        cb[threadIdx.x] = bj;
        ca[threadIdx.x] = (bj.z - bj.x) * (bj.w - bj.y);
    }
    __syncthreads();

    if (r >= NW64 || c < r) return;              // wave below diagonal / OOB
    int i = r * 64 + lane;
    float4 bi = sboxes[(size_t)b * NTOT + (i < NTOT ? i : NTOT - 1)];
    float ax1 = bi.x, ay1 = bi.y, ax2 = bi.z, ay2 = bi.w;
    float area_i = (ax2 - ax1) * (ay2 - ay1);

    u64 m = 0;
    #pragma unroll 8
    for (int k = 0; k < 64; ++k) {
        float4 bj = cb[k];
        float xx1 = fmaxf(bj.x, ax1);
        float yy1 = fmaxf(bj.y, ay1);
        float xx2 = fminf(bj.z, ax2);
        float yy2 = fminf(bj.w, ay2);
        float w = fmaxf(xx2 - xx1, 0.0f);
        float h = fmaxf(yy2 - yy1, 0.0f);
        float inter = w * h;
        float iou = inter / ((area_i + ca[k]) - inter);   // matches ref op order
        bool set = (iou > IOU_THR_F) && (c > r || k > lane) && (c * 64 + k < NTOT);
        m |= (u64)set << k;
    }
    if (i < NTOT) {
        mask[((size_t)b * NTOT + i) * NW64 + c] = m;
        int gi = i >> 8;
        if ((c >> 2) == gi)
            bdiag[(((size_t)b * NG + gi) * 4 + (c & 3)) * 256 + (i & 255)] = m;
        if ((c >> 2) == gi + 1)
            nbdiag[(((size_t)b * NG + gi) * 256 + (i & 255)) * 4 + (c & 3)] = m;
    }
}

// ---------------------------------------------------------------------------
// Kernel C2 (fast path): greedy resolve, one 1024-thread block per image,
// 256 boxes (4 words) per serial iteration -> 42 iterations instead of 167.
// Per group g:
//  * scalar readlane chain over 4 pend words (every wave redundantly; bdiag
//    band lives in 16 u64 regs per thread: lane l holds rows l,64+l,128+l,
//    192+l x 4 words). One step per kept box; sub-diagonal band garbage is
//    dead because ffs processes rows ascending.
//  * kept rows compacted to LDS klist (every wave writes identical values ->
//    no barrier; same-wave LDS ordering guarantees read-back).
//  * word range [4g,4g+4): in-group supp = alive & ~kept (wave 0).
//    [4g+4,4g+8): committed from per-thread nbdiag register (1 u64/thread).
//    [4g+8,..):   loaded this iteration, committed NEXT iteration (deferred;
//    a full iteration of slack hides latency). Iteration is ordered
//    "all consumes before all issues" so even conservative vmcnt(0)
//    placement never waits on just-issued loads.
//  * one raw barrier per group (lgkmcnt drain only; VMEM stays in flight).
//  * nk > 64 (early groups): rare immediate extra rounds.
// ---------------------------------------------------------------------------
static __device__ __forceinline__ void bar_sync()
{
    asm volatile("s_waitcnt lgkmcnt(0)" ::: "memory");
    __builtin_amdgcn_s_barrier();
    asm volatile("" ::: "memory");
}

static __device__ __forceinline__ u64 rfl64(u64 x)
{
    uint32_t lo = __builtin_amdgcn_readfirstlane((uint32_t)x);
    uint32_t hi = __builtin_amdgcn_readfirstlane((uint32_t)(x >> 32));
    return ((u64)hi << 32) | (u64)lo;
}

static __device__ __forceinline__ u64 rl64(u64 x, int lane)
{
    uint32_t lo = (uint32_t)__builtin_amdgcn_readlane((int)(uint32_t)x, lane);
    uint32_t hi = (uint32_t)__builtin_amdgcn_readlane((int)(uint32_t)(x >> 32), lane);
    return ((u64)hi << 32) | (u64)lo;
}

__global__ void __launch_bounds__(1024) resolve_kernel(const u64* __restrict__ mask,
                                                       const u64* __restrict__ bdiag,
                                                       const u64* __restrict__ nbdiag,
                                                       const u64* __restrict__ validbits,
                                                       u64* __restrict__ rem_out)
{
    int b = blockIdx.x;
    int tid = threadIdx.x;
    int lane = tid & 63;
    int wv = tid >> 6;
    const u64* M  = mask   + (size_t)b * NTOT * NW64;
    const u64* BD = bdiag  + (size_t)b * NG * 1024;
    const u64* NB = nbdiag + (size_t)b * NG * 1024;
    const u64* V  = validbits + (size_t)b * NW64;

    __shared__ u64 rem_s[NW64 + 1];
    __shared__ u64 v_s[NW64 + 1];
    __shared__ int klist[256];

    for (int t = tid; t < NW64; t += 1024) { rem_s[t] = 0ull; v_s[t] = V[t]; }
    if (tid == 0) { rem_s[NW64] = 0ull; v_s[NW64] = 0ull; klist[0] = 0; }

    // band registers for group 0 (all accesses compile-time indexed)
    u64 bd[4][4];
    #pragma unroll
    for (int p = 0; p < 4; ++p)
        #pragma unroll
        for (int w = 0; w < 4; ++w)
            bd[p][w] = BD[(size_t)w * 256 + (p << 6) + lane];
    u64 nb_cur = NB[tid];

    u64 df[4][3];
    #pragma unroll
    for (int t = 0; t < 4; ++t) {
        #pragma unroll
        for (int c = 0; c < 3; ++c) df[t][c] = 0ull;
    }

    bar_sync();

    for (int g = 0; g < NG; ++g) {
        // ---- decide: scalar readlane greedy chain over 4 words (uniform) ----
        u64 a0 = rfl64(v_s[4 * g + 0] & ~rem_s[4 * g + 0]);
        u64 a1 = rfl64(v_s[4 * g + 1] & ~rem_s[4 * g + 1]);
        u64 a2 = rfl64(v_s[4 * g + 2] & ~rem_s[4 * g + 2]);
        u64 a3 = rfl64(v_s[4 * g + 3] & ~rem_s[4 * g + 3]);
        u64 p0 = a0, p1 = a1, p2 = a2, p3 = a3;
        u64 k0 = 0, k1 = 0, k2 = 0, k3 = 0;
        while ((p0 | p1 | p2 | p3) != 0ull) {
            if (p0) {
                int il = __ffsll((unsigned long long)p0) - 1; u64 bit = 1ull << il;
                u64 d0 = rl64(bd[0][0], il) | bit;
                u64 d1 = rl64(bd[0][1], il);
                u64 d2 = rl64(bd[0][2], il);
                u64 d3 = rl64(bd[0][3], il);
                k0 |= bit; p0 &= ~d0; p1 &= ~d1; p2 &= ~d2; p3 &= ~d3;
            } else if (p1) {
                int il = __ffsll((unsigned long long)p1) - 1; u64 bit = 1ull << il;
                u64 d0 = rl64(bd[1][0], il);
                u64 d1 = rl64(bd[1][1], il) | bit;
                u64 d2 = rl64(bd[1][2], il);
                u64 d3 = rl64(bd[1][3], il);
                k1 |= bit; p0 &= ~d0; p1 &= ~d1; p2 &= ~d2; p3 &= ~d3;
            } else if (p2) {
                int il = __ffsll((unsigned long long)p2) - 1; u64 bit = 1ull << il;
                u64 d0 = rl64(bd[2][0], il);
                u64 d1 = rl64(bd[2][1], il);
                u64 d2 = rl64(bd[2][2], il) | bit;
                u64 d3 = rl64(bd[2][3], il);
                k2 |= bit; p0 &= ~d0; p1 &= ~d1; p2 &= ~d2; p3 &= ~d3;
            } else {
                int il = __ffsll((unsigned long long)p3) - 1; u64 bit = 1ull << il;
                u64 d0 = rl64(bd[3][0], il);
                u64 d1 = rl64(bd[3][1], il);
                u64 d2 = rl64(bd[3][2], il);
                u64 d3 = rl64(bd[3][3], il) | bit;
                k3 |= bit; p0 &= ~d0; p1 &= ~d1; p2 &= ~d2; p3 &= ~d3;
            }
        }
        int c0 = __popcll(k0);
        int c1 = c0 + __popcll(k1);
        int c2 = c1 + __popcll(k2);
        int nk = c2 + __popcll(k3);

        // ---- compact kept rows into klist (every wave writes same values) ----
        u64 below = (1ull << lane) - 1;
        if ((k0 >> lane) & 1) klist[__popcll(k0 & below)]      = lane;
        if ((k1 >> lane) & 1) klist[c0 + __popcll(k1 & below)] = 64 + lane;
        if ((k2 >> lane) & 1) klist[c1 + __popcll(k2 & below)] = 128 + lane;
        if ((k3 >> lane) & 1) klist[c2 + __popcll(k3 & below)] = 192 + lane;

        // ---- commit deferred far-ORs from group g-1 (targets >= 4g+4) ----
        #pragma unroll
        for (int t = 0; t < 4; ++t) {
            #pragma unroll
            for (int c = 0; c < 3; ++c) {
                if (df[t][c])
                    atomicOr((unsigned long long*)&rem_s[4 * g + 4 + (c << 6) + lane],
                             (unsigned long long)df[t][c]);
            }
        }

        // ---- in-group suppressions (benign race: only adds suppressed bits) ----
        if (tid < 4) {
            u64 av = (tid == 0) ? a0 : (tid == 1) ? a1 : (tid == 2) ? a2 : a3;
            u64 kk = (tid == 0) ? k0 : (tid == 1) ? k1 : (tid == 2) ? k2 : k3;
            u64 supp = av & ~kk;
            int w = 4 * g + tid;
            if (supp && w < NW64) atomicOr((unsigned long long*)&rem_s[w], (unsigned long long)supp);
        }

        // ---- near words [4g+4,4g+8): per-thread nbdiag register ----
        {
            int row = tid >> 2;
            u64 kp = (row < 64) ? k0 : (row < 128) ? k1 : (row < 192) ? k2 : k3;
            if ((kp >> (row & 63)) & 1) {
                int w = 4 * (g + 1) + (tid & 3);
                if (nb_cur && w < NW64)
                    atomicOr((unsigned long long*)&rem_s[w], (unsigned long long)nb_cur);
            }
        }

        // ---- issue far loads (words >= 4g+8), deferred to next iteration ----
        int nk0 = (nk < 64) ? nk : 64;
        #pragma unroll
        for (int t = 0; t < 4; ++t) {
            int s = wv + (t << 4);
            bool has = s < nk0;
            int rr = klist[has ? s : 0];
            int grow = (g << 8) + rr; if (grow >= NTOT) grow = NTOT - 1;
            const u64* R = M + (size_t)grow * NW64;
            #pragma unroll
            for (int c = 0; c < 3; ++c) {
                int w = 4 * g + 8 + (c << 6) + lane;
                df[t][c] = (has && w < NW64) ? R[w] : 0ull;
            }
        }

        // ---- rare: nk > 64 (early groups) -> immediate extra rounds ----
        for (int base = 64; base < nk; base += 64) {
            #pragma unroll
            for (int t = 0; t < 4; ++t) {
                int s = base + wv + (t << 4);
                bool has = s < nk;
                int rr = klist[has ? s : 0];
                int grow = (g << 8) + rr; if (grow >= NTOT) grow = NTOT - 1;
                const u64* R = M + (size_t)grow * NW64;
                #pragma unroll
                for (int c = 0; c < 3; ++c) {
                    int w = 4 * g + 8 + (c << 6) + lane;
                    u64 v2 = (has && w < NW64) ? R[w] : 0ull;
                    if (v2) atomicOr((unsigned long long*)&rem_s[w], (unsigned long long)v2);
                }
            }
        }

        // ---- prefetch next group's bands (consumed after next barrier) ----
        int gn = (g + 1 < NG) ? g + 1 : g;
        #pragma unroll
        for (int p = 0; p < 4; ++p)
            #pragma unroll
            for (int w = 0; w < 4; ++w)
                bd[p][w] = BD[(size_t)(gn * 4 + w) * 256 + (p << 6) + lane];
        nb_cur = NB[(size_t)gn * 1024 + tid];

        bar_sync();                               // LDS coherent; VMEM in flight
    }

    for (int t = tid; t < NW64; t += 1024)
        rem_out[(size_t)b * NW64 + t] = rem_s[t];
}

// ---------------------------------------------------------------------------
// Fallback (small ws): original single-block NMS. Writes u32 words into the
// same u64 rem buffer (little-endian layout makes bit positions identical).
// ---------------------------------------------------------------------------
extern __shared__ unsigned char nms_smem[];

__global__ void __launch_bounds__(1024) nms_kernel(const float4* __restrict__ sboxes,
                                                   const uint32_t* __restrict__ ssv,
                                                   const int* __restrict__ nvalid_arr,
                                                   uint32_t* __restrict__ supp_out)
{
#pragma clang fp contract(off)
    int b = blockIdx.x;
    float4*   lbox = (float4*)nms_smem;
    uint32_t* supp = (uint32_t*)(nms_smem + (size_t)LDS_CAP * 16);
    uint32_t* svb  = supp + NW32;

    int nv = nvalid_arr[b];
    const float4* gb = sboxes + (size_t)b * NTOT;
    const uint32_t* gv = ssv + (size_t)b * NTOT;

    for (int t = threadIdx.x; t < NW32; t += 1024) { supp[t] = 0u; svb[t] = 0u; }
    __syncthreads();
    for (int t = threadIdx.x; t < nv; t += 1024) {
        if (t < LDS_CAP) lbox[t] = gb[t];
        if (gv[t]) atomicOr(&svb[t >> 5], 1u << (t & 31));
    }
    __syncthreads();

    for (int i = 0; i < nv; ++i) {
        uint32_t sw = supp[i >> 5];
        if ((sw >> (i & 31)) & 1u) continue;
        uint32_t vw = svb[i >> 5];
        if (!((vw >> (i & 31)) & 1u)) continue;

        float4 bi = (i < LDS_CAP) ? lbox[i] : gb[i];
        float ax1 = bi.x, ay1 = bi.y, ax2 = bi.z, ay2 = bi.w;
        float area_i = (ax2 - ax1) * (ay2 - ay1);

        for (int j = i + 1 + (int)threadIdx.x; j < nv; j += 1024) {
            float4 bj = (j < LDS_CAP) ? lbox[j] : gb[j];
            float xx1 = fmaxf(bj.x, ax1);
            float yy1 = fmaxf(bj.y, ay1);
            float xx2 = fminf(bj.z, ax2);
            float yy2 = fminf(bj.w, ay2);
            float w = fmaxf(xx2 - xx1, 0.0f);
            float h = fmaxf(yy2 - yy1, 0.0f);
            float inter  = w * h;
            float area_j = (bj.z - bj.x) * (bj.w - bj.y);
            float iou = inter / ((area_i + area_j) - inter);
            if (iou > IOU_THR_F) atomicOr(&supp[j >> 5], 1u << (j & 31));
        }
        __syncthreads();
    }

    __syncthreads();
    // u64 layout: u32 word w of image b lives at u32-index b*(2*NW64) + w
    for (int t = threadIdx.x; t < NW32; t += 1024)
        supp_out[(size_t)b * (2 * NW64) + t] = supp[t];
}

// ---------------------------------------------------------------------------
// Kernel D: assemble outputs: dets [B,N,6] then keep [B,N] (as 0/1 floats)
// ---------------------------------------------------------------------------
__global__ void out_kernel(const float4* __restrict__ sboxes, const float* __restrict__ sscore,
                           const int* __restrict__ scls, const uint32_t* __restrict__ ssv,
                           const u64* __restrict__ rem, float* __restrict__ out)
{
    int idx = blockIdx.x * 256 + threadIdx.x;
    if (idx >= NBATCH * NTOT) return;
    int b = idx / NTOT;
    int p = idx - b * NTOT;

    float4 box = sboxes[idx];
    u64 rw = rem[(size_t)b * NW64 + (p >> 6)];
    bool keep = (ssv[idx] != 0u) && !((rw >> (p & 63)) & 1ull);
    float sc = keep ? sscore[idx] : 0.0f;

    float* d = out + (size_t)idx * 6;
    d[0] = box.x; d[1] = box.y; d[2] = box.z; d[3] = box.w;
    d[4] = sc;    d[5] = (float)scls[idx];
    out[(size_t)NBATCH * NTOT * 6 + idx] = keep ? 1.0f : 0.0f;
}

// ---------------------------------------------------------------------------
extern "C" void kernel_launch(void* const* d_in, const int* in_sizes, int n_in,
                              void* d_out, int out_size, void* d_ws, size_t ws_size,
                              hipStream_t stream)
{
    const float* p3b = (const float*)d_in[0];
    const float* p3c = (const float*)d_in[1];
    const float* p3k = (const float*)d_in[2];
    const float* p4b = (const float*)d_in[3];
    const float* p4c = (const float*)d_in[4];
    const float* p4k = (const float*)d_in[5];
    const float* p5b = (const float*)d_in[6];
    const float* p5c = (const float*)d_in[7];
    const float* p5k = (const float*)d_in[8];
    float* out = (float*)d_out;

    // workspace carve-up (256B aligned slabs)
    char* ws = (char*)d_ws;
    size_t off = 0;
    auto alloc = [&](size_t bytes) { size_t o = off; off += (bytes + 255) & ~(size_t)255; return o; };
    const size_t BN = (size_t)NBATCH * NTOT;
    uint64_t* keys      = (uint64_t*)(ws + alloc(BN * 8));
    float4*   boxes_cat = (float4*)  (ws + alloc(BN * 16));
    float*    score     = (float*)   (ws + alloc(BN * 4));
    int*      clsidx    = (int*)     (ws + alloc(BN * 4));
    uint32_t* sv        = (uint32_t*)(ws + alloc(BN * 4));
    float4*   sboxes    = (float4*)  (ws + alloc(BN * 16));
    float*    sscore    = (float*)   (ws + alloc(BN * 4));
    int*      scls      = (int*)     (ws + alloc(BN * 4));
    uint32_t* ssv       = (uint32_t*)(ws + alloc(BN * 4));
    u64*      rem64     = (u64*)     (ws + alloc((size_t)NBATCH * NW64 * 8));
    u64*      validbits = (u64*)     (ws + alloc((size_t)NBATCH * NW64 * 8));
    int*      nvalid    = (int*)     (ws + alloc(NBATCH * 4));
    u64*      bdiag     = (u64*)     (ws + alloc((size_t)NBATCH * NG * 1024 * 8));
    u64*      nbdiag    = (u64*)     (ws + alloc((size_t)NBATCH * NG * 1024 * 8));
    u64*      mask      = (u64*)     (ws + alloc((size_t)NBATCH * NTOT * NW64 * 8));
    bool fast = (off <= ws_size);

    hipMemsetAsync(nvalid, 0, NBATCH * 4, stream);
    hipMemsetAsync(validbits, 0, (size_t)NBATCH * NW64 * 8, stream);

    int nblk = (int)((BN + 255) / 256);
    prep_kernel<<<nblk, 256, 0, stream>>>(p3b, p3c, p3k, p4b, p4c, p4k, p5b, p5c, p5k,
                                          keys, boxes_cat, score, clsidx, sv);

    dim3 rgrid((NTOT + 255) / 256, NBATCH);
    rank_kernel<<<rgrid, 256, 0, stream>>>(keys, boxes_cat, score, clsidx, sv,
                                           sboxes, sscore, scls, ssv, validbits, nvalid);

    if (fast) {
        dim3 mgrid((NW64 + 3) / 4, NW64, NBATCH);
        mask_build<<<mgrid, 256, 0, stream>>>(sboxes, mask, bdiag, nbdiag);
        resolve_kernel<<<NBATCH, 1024, 0, stream>>>(mask, bdiag, nbdiag, validbits, rem64);
    } else {
        hipMemsetAsync(rem64, 0, (size_t)NBATCH * NW64 * 8, stream);
        size_t smem = (size_t)LDS_CAP * 16 + (size_t)NW32 * 4 * 2;
        smem = (smem + 15) & ~(size_t)15;
        hipFuncSetAttribute((const void*)nms_kernel, hipFuncAttributeMaxDynamicSharedMemorySize, (int)smem);
        nms_kernel<<<NBATCH, 1024, smem, stream>>>(sboxes, ssv, nvalid, (uint32_t*)rem64);
    }

    out_kernel<<<nblk, 256, 0, stream>>>(sboxes, sscore, scls, ssv, rem64, out);
}